// Round 1
// baseline (8484.123 us; speedup 1.0000x reference)
//
#include <hip/hip_runtime.h>
#include <stdint.h>

#define H_ 1024
#define NG_ 4096   // 4*H

typedef float f32x4 __attribute__((ext_vector_type(4)));
typedef __bf16 bf16x8 __attribute__((ext_vector_type(8)));

__device__ __forceinline__ unsigned short f2bf(float f) {
  union { float f; uint32_t u; } v; v.f = f;
  uint32_t r = v.u + 0x7FFFu + ((v.u >> 16) & 1u);
  return (unsigned short)(r >> 16);
}
__device__ __forceinline__ float bf2f(unsigned short b) {
  union { uint32_t u; float f; } v; v.u = ((uint32_t)b) << 16; return v.f;
}

__device__ __forceinline__ void gload_lds16(const void* g, void* l) {
  __builtin_amdgcn_global_load_lds(
      (const __attribute__((address_space(1))) void*)g,
      (__attribute__((address_space(3))) void*)l, 16, 0, 0);
}

__device__ __forceinline__ float sigm(float x) { return 1.f / (1.f + __expf(-x)); }
__device__ __forceinline__ float tanh_(float x) { return 1.f - 2.f / (__expf(2.f * x) + 1.f); }

// ---------------------------------------------------------------------------
// Weight prep: permute rows r = (j>>4)*64 + gate*16 + (j&15)  (old = gate*H + j)
// so a 64-wide column group holds 16 units x 4 gates, gate index = frag index.
// ---------------------------------------------------------------------------
__global__ void prep_w0(const float* __restrict__ Whh0, unsigned short* __restrict__ Wr) {
  int i = (blockIdx.x * 256 + threadIdx.x) * 4;           // over 4096*1024
  int r = i >> 10, k = i & 1023;
  int gate = (r >> 4) & 3;
  int j = ((r >> 6) << 4) + (r & 15);
  const float4 v = *(const float4*)(Whh0 + (size_t)(gate * H_ + j) * H_ + k);
  ushort4 o; o.x = f2bf(v.x); o.y = f2bf(v.y); o.z = f2bf(v.z); o.w = f2bf(v.w);
  *(ushort4*)(Wr + i) = o;
}

__global__ void prep_wcat(const float* __restrict__ Wih1, const float* __restrict__ Whh1,
                          unsigned short* __restrict__ Wr) {
  int i = (blockIdx.x * 256 + threadIdx.x) * 4;           // over 4096*2048
  int r = i >> 11, k = i & 2047;
  int gate = (r >> 4) & 3;
  int j = ((r >> 6) << 4) + (r & 15);
  const float* src = (k < 1024) ? (Wih1 + (size_t)(gate * H_ + j) * H_ + k)
                                : (Whh1 + (size_t)(gate * H_ + j) * H_ + (k - 1024));
  const float4 v = *(const float4*)src;
  ushort4 o; o.x = f2bf(v.x); o.y = f2bf(v.y); o.z = f2bf(v.z); o.w = f2bf(v.w);
  *(ushort4*)(Wr + (size_t)r * 2048 + k) = o;
}

__global__ void prep_small(const float* __restrict__ Wih0,
                           const float* __restrict__ bih0, const float* __restrict__ bhh0,
                           const float* __restrict__ bih1, const float* __restrict__ bhh1,
                           float* __restrict__ bias0r, float* __restrict__ bias1r,
                           float* __restrict__ wi0r) {
  int r = blockIdx.x * 256 + threadIdx.x;                 // over 4096
  int gate = (r >> 4) & 3;
  int j = ((r >> 6) << 4) + (r & 15);
  int old = gate * H_ + j;
  bias0r[r] = bih0[old] + bhh0[old];
  bias1r[r] = bih1[old] + bhh1[old];
  wi0r[r * 2 + 0] = Wih0[old * 2 + 0];
  wi0r[r * 2 + 1] = Wih0[old * 2 + 1];
}

__global__ void prep_state(const float* __restrict__ h, const float* __restrict__ c,
                           unsigned short* __restrict__ h0b, unsigned short* __restrict__ h1b,
                           float* __restrict__ c0, float* __restrict__ c1, int bh) {
  int i = (blockIdx.x * 256 + threadIdx.x) * 4;           // over B*H
  float4 a = *(const float4*)(h + i);
  float4 b = *(const float4*)(h + (size_t)bh + i);
  ushort4 oa; oa.x = f2bf(a.x); oa.y = f2bf(a.y); oa.z = f2bf(a.z); oa.w = f2bf(a.w);
  ushort4 ob; ob.x = f2bf(b.x); ob.y = f2bf(b.y); ob.z = f2bf(b.z); ob.w = f2bf(b.w);
  *(ushort4*)(h0b + i) = oa;
  *(ushort4*)(h1b + i) = ob;
  *(float4*)(c0 + i) = *(const float4*)(c + i);
  *(float4*)(c1 + i) = *(const float4*)(c + (size_t)bh + i);
}

// ---------------------------------------------------------------------------
// Fused GEMM + LSTM cell.
//   G = A @ Bw^T (+bias)(+W_ih0[:,x])  -> cell -> writes h (bf16) and c (f32)
// A is the K-concat of A0 (k<1024) and A1 (k>=1024), both (B,1024) bf16.
// 128x128 tile, BK=64, 4 waves (2x2), mfma 16x16x32 bf16. m97-style staging.
// ---------------------------------------------------------------------------
__global__ void lstm_gemm_cell(const unsigned short* __restrict__ A0,
                               const unsigned short* __restrict__ A1,
                               int Ktot,
                               const unsigned short* __restrict__ Bw,
                               const float* __restrict__ biasr,
                               const float* __restrict__ wi0r,
                               const int* __restrict__ xidx,
                               int have_x,
                               float* __restrict__ Cst,
                               unsigned short* __restrict__ Hout) {
  __shared__ unsigned short As[128 * 64];
  __shared__ unsigned short Bs[128 * 64];
  const int tid  = threadIdx.x;
  const int lane = tid & 63;
  const int wv   = tid >> 6;
  const int wm   = wv >> 1, wn = wv & 1;
  const int tile_m = blockIdx.y * 128;
  const int tile_n = blockIdx.x * 128;

  f32x4 acc[4][4];
#pragma unroll
  for (int m = 0; m < 4; ++m)
#pragma unroll
    for (int n = 0; n < 4; ++n) acc[m][n] = (f32x4)0.f;

  const int lrow = lane >> 3;        // 0..7 within 8-row chunk
  const int lk   = (lane & 7) * 8;   // k element offset 0..56

  const int nk = Ktot >> 6;
  for (int kt = 0; kt < nk; ++kt) {
    const int k0 = kt << 6;
    const unsigned short* Ap; int kl;
    if (k0 < 1024) { Ap = A0; kl = k0; } else { Ap = A1; kl = k0 - 1024; }
#pragma unroll
    for (int i = 0; i < 4; ++i) {
      int chunk = wv * 4 + i;
      int row = chunk * 8 + lrow;
      gload_lds16(Ap + (size_t)(tile_m + row) * H_ + kl + lk, (void*)&As[chunk * 512]);
    }
#pragma unroll
    for (int i = 0; i < 4; ++i) {
      int chunk = wv * 4 + i;
      int row = chunk * 8 + lrow;
      gload_lds16(Bw + (size_t)(tile_n + row) * Ktot + k0 + lk, (void*)&Bs[chunk * 512]);
    }
    __syncthreads();

    const char* Ab = (const char*)As;
    const char* Bb = (const char*)Bs;
    const int arow = wm * 64 + (lane & 15);
    const int brow = wn * 64 + (lane & 15);
    const int koff = (lane >> 4) * 16;  // bytes
#pragma unroll
    for (int ks = 0; ks < 2; ++ks) {
      bf16x8 af[4], bfr[4];
#pragma unroll
      for (int m = 0; m < 4; ++m)
        af[m] = *(const bf16x8*)(Ab + (arow + m * 16) * 128 + ks * 64 + koff);
#pragma unroll
      for (int n = 0; n < 4; ++n)
        bfr[n] = *(const bf16x8*)(Bb + (brow + n * 16) * 128 + ks * 64 + koff);
#pragma unroll
      for (int m = 0; m < 4; ++m)
#pragma unroll
        for (int n = 0; n < 4; ++n)
          acc[m][n] = __builtin_amdgcn_mfma_f32_16x16x32_bf16(af[m], bfr[n], acc[m][n], 0, 0, 0);
    }
    __syncthreads();
  }

  // ---- epilogue: fused LSTM cell ----
  const int cl = lane & 15;
  const int rq = (lane >> 4) * 4;
  const int jgrp = (tile_n >> 6) + wn;           // (tile_n + wn*64)/64
  const int j = jgrp * 16 + cl;
  float bias[4], w0v[4] = {0,0,0,0}, w1v[4] = {0,0,0,0};
#pragma unroll
  for (int n = 0; n < 4; ++n) {
    int colr = tile_n + wn * 64 + n * 16 + cl;
    bias[n] = biasr[colr];
    if (have_x) { w0v[n] = wi0r[colr * 2]; w1v[n] = wi0r[colr * 2 + 1]; }
  }
#pragma unroll
  for (int m = 0; m < 4; ++m) {
#pragma unroll
    for (int q = 0; q < 4; ++q) {
      int row = tile_m + wm * 64 + m * 16 + rq + q;
      float gi = acc[m][0][q] + bias[0];
      float gf = acc[m][1][q] + bias[1];
      float gg = acc[m][2][q] + bias[2];
      float go = acc[m][3][q] + bias[3];
      if (have_x) {
        int x = xidx[row];
        gi += x ? w1v[0] : w0v[0];
        gf += x ? w1v[1] : w0v[1];
        gg += x ? w1v[2] : w0v[2];
        go += x ? w1v[3] : w0v[3];
      }
      size_t off = (size_t)row * H_ + j;
      float cp = Cst[off];
      float cn = sigm(gf) * cp + sigm(gi) * tanh_(gg);
      float hn = sigm(go) * tanh_(cn);
      Cst[off] = cn;
      Hout[off] = f2bf(hn);
    }
  }
}

// ---------------------------------------------------------------------------
// fc head: logits = h1 @ fcW^T + fcb, write out[b,t,:], argmax -> xidx
// one wave per batch row.
// ---------------------------------------------------------------------------
__global__ void fc_argmax(const unsigned short* __restrict__ h1,
                          const float* __restrict__ fcW, const float* __restrict__ fcb,
                          float* __restrict__ out, int* __restrict__ xidx,
                          int t, int pred_len) {
  const int lane = threadIdx.x & 63;
  const int wv = threadIdx.x >> 6;
  const int row = blockIdx.x * 4 + wv;
  const unsigned short* hp = h1 + (size_t)row * H_ + lane * 16;
  float d0 = 0.f, d1 = 0.f;
#pragma unroll
  for (int u = 0; u < 2; ++u) {
    ushort4 ha = *(const ushort4*)(hp + u * 8);
    ushort4 hb = *(const ushort4*)(hp + u * 8 + 4);
    float hv[8] = { bf2f(ha.x), bf2f(ha.y), bf2f(ha.z), bf2f(ha.w),
                    bf2f(hb.x), bf2f(hb.y), bf2f(hb.z), bf2f(hb.w) };
#pragma unroll
    for (int e = 0; e < 8; ++e) {
      int k = lane * 16 + u * 8 + e;
      d0 += hv[e] * fcW[k];
      d1 += hv[e] * fcW[H_ + k];
    }
  }
#pragma unroll
  for (int off = 32; off > 0; off >>= 1) {
    d0 += __shfl_xor(d0, off);
    d1 += __shfl_xor(d1, off);
  }
  if (lane == 0) {
    d0 += fcb[0]; d1 += fcb[1];
    size_t o = ((size_t)row * pred_len + t) * 2;
    out[o] = d0; out[o + 1] = d1;
    xidx[row] = (d1 > d0) ? 1 : 0;
  }
}

// ---------------------------------------------------------------------------
extern "C" void kernel_launch(void* const* d_in, const int* in_sizes, int n_in,
                              void* d_out, int out_size, void* d_ws, size_t ws_size,
                              hipStream_t stream) {
  const float* h     = (const float*)d_in[0];
  const float* c     = (const float*)d_in[1];
  const float* Wih0  = (const float*)d_in[2];
  const float* Whh0  = (const float*)d_in[3];
  const float* bih0  = (const float*)d_in[4];
  const float* bhh0  = (const float*)d_in[5];
  const float* Wih1  = (const float*)d_in[6];
  const float* Whh1  = (const float*)d_in[7];
  const float* bih1  = (const float*)d_in[8];
  const float* bhh1  = (const float*)d_in[9];
  const float* fcW   = (const float*)d_in[10];
  const float* fcb   = (const float*)d_in[11];

  const int B = in_sizes[0] / (2 * H_);           // 4096
  const int pred_len = out_size / (B * 2);        // 64
  const int BH = B * H_;                          // 4194304

  // workspace carve-up
  size_t off = 0;
  auto carve = [&](size_t bytes) -> void* {
    void* p = (char*)d_ws + off;
    off += (bytes + 255) & ~(size_t)255;
    return p;
  };
  unsigned short* Whh0r = (unsigned short*)carve((size_t)NG_ * 1024 * 2);
  unsigned short* Wcatr = (unsigned short*)carve((size_t)NG_ * 2048 * 2);
  unsigned short* h0b[2], *h1b[2];
  h0b[0] = (unsigned short*)carve((size_t)BH * 2);
  h0b[1] = (unsigned short*)carve((size_t)BH * 2);
  h1b[0] = (unsigned short*)carve((size_t)BH * 2);
  h1b[1] = (unsigned short*)carve((size_t)BH * 2);
  float* c0 = (float*)carve((size_t)BH * 4);
  float* c1 = (float*)carve((size_t)BH * 4);
  float* bias0r = (float*)carve(NG_ * 4);
  float* bias1r = (float*)carve(NG_ * 4);
  float* wi0r   = (float*)carve(NG_ * 2 * 4);
  int*   xidx   = (int*)carve(B * 4);

  // prep
  hipLaunchKernelGGL(prep_w0,   dim3((NG_ * 1024 / 4) / 256), dim3(256), 0, stream, Whh0, Whh0r);
  hipLaunchKernelGGL(prep_wcat, dim3((NG_ * 2048 / 4) / 256), dim3(256), 0, stream, Wih1, Whh1, Wcatr);
  hipLaunchKernelGGL(prep_small, dim3(NG_ / 256), dim3(256), 0, stream,
                     Wih0, bih0, bhh0, bih1, bhh1, bias0r, bias1r, wi0r);
  hipLaunchKernelGGL(prep_state, dim3((BH / 4) / 256), dim3(256), 0, stream,
                     h, c, h0b[0], h1b[0], c0, c1, BH);

  dim3 ggrid(NG_ / 128, B / 128);
  dim3 gblk(256);
  float* out = (float*)d_out;

  for (int t = 0; t < pred_len; ++t) {
    const int cur = t & 1, nxt = cur ^ 1;
    // layer 0: G0 = h0 @ Whh0^T (+ bias)(+ Wih0[:,x]) -> h0b[nxt], c0
    hipLaunchKernelGGL(lstm_gemm_cell, ggrid, gblk, 0, stream,
                       h0b[cur], (const unsigned short*)nullptr, 1024, Whh0r,
                       bias0r, wi0r, xidx, (t > 0) ? 1 : 0, c0, h0b[nxt]);
    // layer 1: G1 = [h0n | h1] @ [Wih1|Whh1]^T (+ bias) -> h1b[nxt], c1
    hipLaunchKernelGGL(lstm_gemm_cell, ggrid, gblk, 0, stream,
                       h0b[nxt], h1b[cur], 2048, Wcatr,
                       bias1r, (const float*)nullptr, (const int*)nullptr, 0, c1, h1b[nxt]);
    // fc head + argmax feedback
    hipLaunchKernelGGL(fc_argmax, dim3(B / 4), dim3(256), 0, stream,
                       h1b[nxt], fcW, fcb, out, xidx, t, pred_len);
  }
}

// Round 2
// 8121.226 us; speedup vs baseline: 1.0447x; 1.0447x over previous
//
#include <hip/hip_runtime.h>
#include <stdint.h>

#define H_ 1024
#define NG_ 4096   // 4*H

typedef float f32x4 __attribute__((ext_vector_type(4)));
typedef __bf16 bf16x8 __attribute__((ext_vector_type(8)));

__device__ __forceinline__ unsigned short f2bf(float f) {
  union { float f; uint32_t u; } v; v.f = f;
  uint32_t r = v.u + 0x7FFFu + ((v.u >> 16) & 1u);
  return (unsigned short)(r >> 16);
}
__device__ __forceinline__ float bf2f(unsigned short b) {
  union { uint32_t u; float f; } v; v.u = ((uint32_t)b) << 16; return v.f;
}

__device__ __forceinline__ void gload_lds16(const void* g, void* l) {
  __builtin_amdgcn_global_load_lds(
      (const __attribute__((address_space(1))) void*)g,
      (__attribute__((address_space(3))) void*)l, 16, 0, 0);
}

__device__ __forceinline__ float sigm(float x) { return 1.f / (1.f + __expf(-x)); }
__device__ __forceinline__ float tanh_(float x) { return 1.f - 2.f / (__expf(2.f * x) + 1.f); }

// ---------------------------------------------------------------------------
// Weight prep: permute rows r = (j>>4)*64 + gate*16 + (j&15)  (old = gate*H + j)
// so a 64-wide column group holds 16 units x 4 gates, gate index = n-frag index.
// ---------------------------------------------------------------------------
__global__ void prep_w0(const float* __restrict__ Whh0, unsigned short* __restrict__ Wr) {
  int i = (blockIdx.x * 256 + threadIdx.x) * 4;           // over 4096*1024
  int r = i >> 10, k = i & 1023;
  int gate = (r >> 4) & 3;
  int j = ((r >> 6) << 4) + (r & 15);
  const float4 v = *(const float4*)(Whh0 + (size_t)(gate * H_ + j) * H_ + k);
  ushort4 o; o.x = f2bf(v.x); o.y = f2bf(v.y); o.z = f2bf(v.z); o.w = f2bf(v.w);
  *(ushort4*)(Wr + i) = o;
}

__global__ void prep_wcat(const float* __restrict__ Wih1, const float* __restrict__ Whh1,
                          unsigned short* __restrict__ Wr) {
  int i = (blockIdx.x * 256 + threadIdx.x) * 4;           // over 4096*2048
  int r = i >> 11, k = i & 2047;
  int gate = (r >> 4) & 3;
  int j = ((r >> 6) << 4) + (r & 15);
  const float* src = (k < 1024) ? (Wih1 + (size_t)(gate * H_ + j) * H_ + k)
                                : (Whh1 + (size_t)(gate * H_ + j) * H_ + (k - 1024));
  const float4 v = *(const float4*)src;
  ushort4 o; o.x = f2bf(v.x); o.y = f2bf(v.y); o.z = f2bf(v.z); o.w = f2bf(v.w);
  *(ushort4*)(Wr + (size_t)r * 2048 + k) = o;
}

__global__ void prep_small(const float* __restrict__ Wih0,
                           const float* __restrict__ bih0, const float* __restrict__ bhh0,
                           const float* __restrict__ bih1, const float* __restrict__ bhh1,
                           float* __restrict__ bias0r, float* __restrict__ bias1r,
                           float* __restrict__ wi0r) {
  int r = blockIdx.x * 256 + threadIdx.x;                 // over 4096
  int gate = (r >> 4) & 3;
  int j = ((r >> 6) << 4) + (r & 15);
  int old = gate * H_ + j;
  bias0r[r] = bih0[old] + bhh0[old];
  bias1r[r] = bih1[old] + bhh1[old];
  wi0r[r * 2 + 0] = Wih0[old * 2 + 0];
  wi0r[r * 2 + 1] = Wih0[old * 2 + 1];
}

__global__ void prep_state(const float* __restrict__ h, const float* __restrict__ c,
                           unsigned short* __restrict__ h0b, unsigned short* __restrict__ h1b,
                           float* __restrict__ c0, float* __restrict__ c1, int bh) {
  int i = (blockIdx.x * 256 + threadIdx.x) * 4;           // over B*H
  float4 a = *(const float4*)(h + i);
  float4 b = *(const float4*)(h + (size_t)bh + i);
  ushort4 oa; oa.x = f2bf(a.x); oa.y = f2bf(a.y); oa.z = f2bf(a.z); oa.w = f2bf(a.w);
  ushort4 ob; ob.x = f2bf(b.x); ob.y = f2bf(b.y); ob.z = f2bf(b.z); ob.w = f2bf(b.w);
  *(ushort4*)(h0b + i) = oa;
  *(ushort4*)(h1b + i) = ob;
  *(float4*)(c0 + i) = *(const float4*)(c + i);
  *(float4*)(c1 + i) = *(const float4*)(c + (size_t)bh + i);
}

// ---------------------------------------------------------------------------
// Fused GEMM + LSTM cell, 256x256 tile, BK=64, 8 waves (2M x 4N), 512 thr.
// Double-buffered LDS (128 KiB), counted-vmcnt pipeline, st-style XOR swizzle
// (pre-swizzled global source for global_load_lds + swizzled ds_read).
//   G = A @ Bw^T (+bias)(+W_ih0[:,x])  -> cell -> writes h (bf16) and c (f32)
// A is the K-concat of A0 (k<1024) and A1 (k>=1024), both (B,1024) bf16.
// ---------------------------------------------------------------------------
__global__ void __launch_bounds__(512, 2)
lstm_gemm_cell(const unsigned short* __restrict__ A0,
               const unsigned short* __restrict__ A1,
               int Ktot,
               const unsigned short* __restrict__ Bw,
               const float* __restrict__ biasr,
               const float* __restrict__ wi0r,
               const int* __restrict__ xidx,
               int have_x,
               float* __restrict__ Cst,
               unsigned short* __restrict__ Hout) {
  // 2 dbuf x 256 rows x 64 bf16 each for A and B: 2*(32KB+32KB) = 128 KiB
  __shared__ unsigned short As[2][256 * 64];
  __shared__ unsigned short Bs[2][256 * 64];

  const int tid  = threadIdx.x;
  const int lane = tid & 63;
  const int wv   = tid >> 6;          // 0..7
  const int wm   = wv >> 2;           // 0..1  (M half)
  const int wn   = wv & 3;            // 0..3  (N quarter)
  const int tile_m = blockIdx.y * 256;
  const int tile_n = blockIdx.x * 256;

  // staging geometry: each round = 512 thr x 16B = 64 rows; 4 rounds per tile
  const int rowt = tid >> 3;                          // 0..63 row within round
  const int cb8  = (tid & 7) * 8;                     // LDS col (ushort units), linear dest
  const int ce   = (((tid & 7) ^ (rowt & 7)) * 8);    // global col: inverse-swizzled source

  const int NK = Ktot >> 6;

  auto stage = [&](int d, int kt) {
    const int kb = kt << 6;
    const unsigned short* Ap = A0; int kl = kb;
    if (kb >= 1024) { Ap = A1; kl = kb - 1024; }
#pragma unroll
    for (int i = 0; i < 4; ++i) {
      const int row = i * 64 + rowt;
      gload_lds16(Ap + (size_t)(tile_m + row) * H_ + kl + ce, (void*)&As[d][row * 64 + cb8]);
    }
#pragma unroll
    for (int i = 0; i < 4; ++i) {
      const int row = i * 64 + rowt;
      gload_lds16(Bw + (size_t)(tile_n + row) * (size_t)Ktot + kb + ce, (void*)&Bs[d][row * 64 + cb8]);
    }
  };

  f32x4 acc[8][4];
#pragma unroll
  for (int m = 0; m < 8; ++m)
#pragma unroll
    for (int n = 0; n < 4; ++n) acc[m][n] = (f32x4)0.f;

  // fragment read geometry (swizzled): row r holds logical col kb at byte kb^((r&7)<<4)
  const int cl  = lane & 15;
  const int khi = lane >> 4;          // 0..3
  const int Xn  = lane & 7;           // (row&7) of the rows this lane reads
  const int ksw0 = ((0 + khi) ^ Xn) * 16;   // ks=0: logical nibble khi
  const int ksw1 = ((4 + khi) ^ Xn) * 16;   // ks=1: logical nibble 4+khi

  // ---- prologue: stage K-tiles 0 and 1 ----
  stage(0, 0);
  stage(1, 1);
  asm volatile("s_waitcnt vmcnt(8)" ::: "memory");   // K-tile 0 landed (8 newest = tile 1)
  __builtin_amdgcn_sched_barrier(0);
  __builtin_amdgcn_s_barrier();

  for (int kt = 0; kt < NK; ++kt) {
    const int cur = kt & 1;
    const char* Abase = (const char*)&As[cur][0] + (wm * 128 + cl) * 128;
    const char* Bbase = (const char*)&Bs[cur][0] + (wn * 64 + cl) * 128;

    bf16x8 af0[8], af1[8], bf0[4], bf1[4];
#pragma unroll
    for (int m = 0; m < 8; ++m) {
      af0[m] = *(const bf16x8*)(Abase + m * 2048 + ksw0);
      af1[m] = *(const bf16x8*)(Abase + m * 2048 + ksw1);
    }
#pragma unroll
    for (int n = 0; n < 4; ++n) {
      bf0[n] = *(const bf16x8*)(Bbase + n * 2048 + ksw0);
      bf1[n] = *(const bf16x8*)(Bbase + n * 2048 + ksw1);
    }

    asm volatile("s_waitcnt lgkmcnt(0)" ::: "memory");  // frags in regs
    __builtin_amdgcn_sched_barrier(0);
    __builtin_amdgcn_s_barrier();                        // all waves done reading buf[cur]

    if (kt + 2 < NK) {
      stage(cur, kt + 2);                                // overwrite buf[cur]
      asm volatile("s_waitcnt vmcnt(8)" ::: "memory");   // kt+1 landed; kt+2 stays in flight
    } else {
      asm volatile("s_waitcnt vmcnt(0)" ::: "memory");   // tail: drain
    }
    __builtin_amdgcn_sched_barrier(0);

    __builtin_amdgcn_s_setprio(1);
#pragma unroll
    for (int m = 0; m < 8; ++m)
#pragma unroll
      for (int n = 0; n < 4; ++n)
        acc[m][n] = __builtin_amdgcn_mfma_f32_16x16x32_bf16(af0[m], bf0[n], acc[m][n], 0, 0, 0);
#pragma unroll
    for (int m = 0; m < 8; ++m)
#pragma unroll
      for (int n = 0; n < 4; ++n)
        acc[m][n] = __builtin_amdgcn_mfma_f32_16x16x32_bf16(af1[m], bf1[n], acc[m][n], 0, 0, 0);
    __builtin_amdgcn_s_setprio(0);

    __builtin_amdgcn_s_barrier();                        // kt+1 fully in LDS for next iter
  }

  // ---- epilogue: fused LSTM cell (gate = n-frag index) ----
  const int jgrp = (tile_n >> 6) + wn;
  const int j = jgrp * 16 + cl;
  float bias[4], w0v[4] = {0, 0, 0, 0}, w1v[4] = {0, 0, 0, 0};
#pragma unroll
  for (int n = 0; n < 4; ++n) {
    int colr = tile_n + wn * 64 + n * 16 + cl;
    bias[n] = biasr[colr];
    if (have_x) { w0v[n] = wi0r[colr * 2]; w1v[n] = wi0r[colr * 2 + 1]; }
  }
#pragma unroll
  for (int m = 0; m < 8; ++m) {
#pragma unroll
    for (int q = 0; q < 4; ++q) {
      int row = tile_m + wm * 128 + m * 16 + khi * 4 + q;
      float gi = acc[m][0][q] + bias[0];
      float gf = acc[m][1][q] + bias[1];
      float gg = acc[m][2][q] + bias[2];
      float go = acc[m][3][q] + bias[3];
      if (have_x) {
        int x = xidx[row];
        gi += x ? w1v[0] : w0v[0];
        gf += x ? w1v[1] : w0v[1];
        gg += x ? w1v[2] : w0v[2];
        go += x ? w1v[3] : w0v[3];
      }
      size_t off = (size_t)row * H_ + j;
      float cp = Cst[off];
      float cn = sigm(gf) * cp + sigm(gi) * tanh_(gg);
      float hn = sigm(go) * tanh_(cn);
      Cst[off] = cn;
      Hout[off] = f2bf(hn);
    }
  }
}

// ---------------------------------------------------------------------------
// fc head: logits = h1 @ fcW^T + fcb, write out[b,t,:], argmax -> xidx
// ---------------------------------------------------------------------------
__global__ void fc_argmax(const unsigned short* __restrict__ h1,
                          const float* __restrict__ fcW, const float* __restrict__ fcb,
                          float* __restrict__ out, int* __restrict__ xidx,
                          int t, int pred_len) {
  const int lane = threadIdx.x & 63;
  const int wv = threadIdx.x >> 6;
  const int row = blockIdx.x * 4 + wv;
  const unsigned short* hp = h1 + (size_t)row * H_ + lane * 16;
  float d0 = 0.f, d1 = 0.f;
#pragma unroll
  for (int u = 0; u < 2; ++u) {
    ushort4 ha = *(const ushort4*)(hp + u * 8);
    ushort4 hb = *(const ushort4*)(hp + u * 8 + 4);
    float hv[8] = { bf2f(ha.x), bf2f(ha.y), bf2f(ha.z), bf2f(ha.w),
                    bf2f(hb.x), bf2f(hb.y), bf2f(hb.z), bf2f(hb.w) };
#pragma unroll
    for (int e = 0; e < 8; ++e) {
      int k = lane * 16 + u * 8 + e;
      d0 += hv[e] * fcW[k];
      d1 += hv[e] * fcW[H_ + k];
    }
  }
#pragma unroll
  for (int off = 32; off > 0; off >>= 1) {
    d0 += __shfl_xor(d0, off);
    d1 += __shfl_xor(d1, off);
  }
  if (lane == 0) {
    d0 += fcb[0]; d1 += fcb[1];
    size_t o = ((size_t)row * pred_len + t) * 2;
    out[o] = d0; out[o + 1] = d1;
    xidx[row] = (d1 > d0) ? 1 : 0;
  }
}

// ---------------------------------------------------------------------------
extern "C" void kernel_launch(void* const* d_in, const int* in_sizes, int n_in,
                              void* d_out, int out_size, void* d_ws, size_t ws_size,
                              hipStream_t stream) {
  const float* h     = (const float*)d_in[0];
  const float* c     = (const float*)d_in[1];
  const float* Wih0  = (const float*)d_in[2];
  const float* Whh0  = (const float*)d_in[3];
  const float* bih0  = (const float*)d_in[4];
  const float* bhh0  = (const float*)d_in[5];
  const float* Wih1  = (const float*)d_in[6];
  const float* Whh1  = (const float*)d_in[7];
  const float* bih1  = (const float*)d_in[8];
  const float* bhh1  = (const float*)d_in[9];
  const float* fcW   = (const float*)d_in[10];
  const float* fcb   = (const float*)d_in[11];

  const int B = in_sizes[0] / (2 * H_);           // 4096
  const int pred_len = out_size / (B * 2);        // 64
  const int BH = B * H_;                          // 4194304

  size_t off = 0;
  auto carve = [&](size_t bytes) -> void* {
    void* p = (char*)d_ws + off;
    off += (bytes + 255) & ~(size_t)255;
    return p;
  };
  unsigned short* Whh0r = (unsigned short*)carve((size_t)NG_ * 1024 * 2);
  unsigned short* Wcatr = (unsigned short*)carve((size_t)NG_ * 2048 * 2);
  unsigned short* h0b[2], *h1b[2];
  h0b[0] = (unsigned short*)carve((size_t)BH * 2);
  h0b[1] = (unsigned short*)carve((size_t)BH * 2);
  h1b[0] = (unsigned short*)carve((size_t)BH * 2);
  h1b[1] = (unsigned short*)carve((size_t)BH * 2);
  float* c0 = (float*)carve((size_t)BH * 4);
  float* c1 = (float*)carve((size_t)BH * 4);
  float* bias0r = (float*)carve(NG_ * 4);
  float* bias1r = (float*)carve(NG_ * 4);
  float* wi0r   = (float*)carve(NG_ * 2 * 4);
  int*   xidx   = (int*)carve(B * 4);

  hipLaunchKernelGGL(prep_w0,   dim3((NG_ * 1024 / 4) / 256), dim3(256), 0, stream, Whh0, Whh0r);
  hipLaunchKernelGGL(prep_wcat, dim3((NG_ * 2048 / 4) / 256), dim3(256), 0, stream, Wih1, Whh1, Wcatr);
  hipLaunchKernelGGL(prep_small, dim3(NG_ / 256), dim3(256), 0, stream,
                     Wih0, bih0, bhh0, bih1, bhh1, bias0r, bias1r, wi0r);
  hipLaunchKernelGGL(prep_state, dim3((BH / 4) / 256), dim3(256), 0, stream,
                     h, c, h0b[0], h1b[0], c0, c1, BH);

  dim3 ggrid(NG_ / 256, B / 256);                 // 16 x 16 = 256 blocks (1/CU)
  dim3 gblk(512);
  float* out = (float*)d_out;

  for (int t = 0; t < pred_len; ++t) {
    const int cur = t & 1, nxt = cur ^ 1;
    hipLaunchKernelGGL(lstm_gemm_cell, ggrid, gblk, 0, stream,
                       h0b[cur], (const unsigned short*)nullptr, 1024, Whh0r,
                       bias0r, wi0r, xidx, (t > 0) ? 1 : 0, c0, h0b[nxt]);
    hipLaunchKernelGGL(lstm_gemm_cell, ggrid, gblk, 0, stream,
                       h0b[nxt], h1b[cur], 2048, Wcatr,
                       bias1r, (const float*)nullptr, (const int*)nullptr, 0, c1, h1b[nxt]);
    hipLaunchKernelGGL(fc_argmax, dim3(B / 4), dim3(256), 0, stream,
                       h1b[nxt], fcW, fcb, out, xidx, t, pred_len);
  }
}

// Round 3
// 8042.171 us; speedup vs baseline: 1.0550x; 1.0098x over previous
//
#include <hip/hip_runtime.h>
#include <stdint.h>

#define H_ 1024
#define NG_ 4096   // 4*H

typedef float f32x4 __attribute__((ext_vector_type(4)));
typedef __bf16 bf16x8 __attribute__((ext_vector_type(8)));

__device__ __forceinline__ unsigned short f2bf(float f) {
  union { float f; uint32_t u; } v; v.f = f;
  uint32_t r = v.u + 0x7FFFu + ((v.u >> 16) & 1u);
  return (unsigned short)(r >> 16);
}
__device__ __forceinline__ float bf2f(unsigned short b) {
  union { uint32_t u; float f; } v; v.u = ((uint32_t)b) << 16; return v.f;
}

__device__ __forceinline__ void gload_lds16(const void* g, void* l) {
  __builtin_amdgcn_global_load_lds(
      (const __attribute__((address_space(1))) void*)g,
      (__attribute__((address_space(3))) void*)l, 16, 0, 0);
}

__device__ __forceinline__ float sigm(float x) { return 1.f / (1.f + __expf(-x)); }
__device__ __forceinline__ float tanh_(float x) { return 1.f - 2.f / (__expf(2.f * x) + 1.f); }

// ---------------------------------------------------------------------------
// Weight prep: permute rows r = (j>>4)*64 + gate*16 + (j&15)  (old = gate*H + j)
// so a 64-wide column group holds 16 units x 4 gates, gate index = n-frag index.
// ---------------------------------------------------------------------------
__global__ void prep_w0(const float* __restrict__ Whh0, unsigned short* __restrict__ Wr) {
  int i = (blockIdx.x * 256 + threadIdx.x) * 4;           // over 4096*1024
  int r = i >> 10, k = i & 1023;
  int gate = (r >> 4) & 3;
  int j = ((r >> 6) << 4) + (r & 15);
  const float4 v = *(const float4*)(Whh0 + (size_t)(gate * H_ + j) * H_ + k);
  ushort4 o; o.x = f2bf(v.x); o.y = f2bf(v.y); o.z = f2bf(v.z); o.w = f2bf(v.w);
  *(ushort4*)(Wr + i) = o;
}

__global__ void prep_wcat(const float* __restrict__ Wih1, const float* __restrict__ Whh1,
                          unsigned short* __restrict__ Wr) {
  int i = (blockIdx.x * 256 + threadIdx.x) * 4;           // over 4096*2048
  int r = i >> 11, k = i & 2047;
  int gate = (r >> 4) & 3;
  int j = ((r >> 6) << 4) + (r & 15);
  const float* src = (k < 1024) ? (Wih1 + (size_t)(gate * H_ + j) * H_ + k)
                                : (Whh1 + (size_t)(gate * H_ + j) * H_ + (k - 1024));
  const float4 v = *(const float4*)src;
  ushort4 o; o.x = f2bf(v.x); o.y = f2bf(v.y); o.z = f2bf(v.z); o.w = f2bf(v.w);
  *(ushort4*)(Wr + (size_t)r * 2048 + k) = o;
}

__global__ void prep_small(const float* __restrict__ Wih0,
                           const float* __restrict__ bih0, const float* __restrict__ bhh0,
                           const float* __restrict__ bih1, const float* __restrict__ bhh1,
                           float* __restrict__ bias0r, float* __restrict__ bias1r,
                           float* __restrict__ wi0r) {
  int r = blockIdx.x * 256 + threadIdx.x;                 // over 4096
  int gate = (r >> 4) & 3;
  int j = ((r >> 6) << 4) + (r & 15);
  int old = gate * H_ + j;
  bias0r[r] = bih0[old] + bhh0[old];
  bias1r[r] = bih1[old] + bhh1[old];
  wi0r[r * 2 + 0] = Wih0[old * 2 + 0];
  wi0r[r * 2 + 1] = Wih0[old * 2 + 1];
}

__global__ void prep_state(const float* __restrict__ h, const float* __restrict__ c,
                           unsigned short* __restrict__ h0b, unsigned short* __restrict__ h1b,
                           float* __restrict__ c0, float* __restrict__ c1, int bh) {
  int i = (blockIdx.x * 256 + threadIdx.x) * 4;           // over B*H
  float4 a = *(const float4*)(h + i);
  float4 b = *(const float4*)(h + (size_t)bh + i);
  ushort4 oa; oa.x = f2bf(a.x); oa.y = f2bf(a.y); oa.z = f2bf(a.z); oa.w = f2bf(a.w);
  ushort4 ob; ob.x = f2bf(b.x); ob.y = f2bf(b.y); ob.z = f2bf(b.z); ob.w = f2bf(b.w);
  *(ushort4*)(h0b + i) = oa;
  *(ushort4*)(h1b + i) = ob;
  *(float4*)(c0 + i) = *(const float4*)(c + i);
  *(float4*)(c1 + i) = *(const float4*)(c + (size_t)bh + i);
}

// ---------------------------------------------------------------------------
// Fused GEMM + LSTM cell, 256x256 tile, BK=64, 8 waves (2M x 4N), 512 thr.
// TRUE 8-phase schedule (T3+T4+T5): per K-tile, 4 quadrant-phases of 16 MFMA
// each, with ds_read || half-tile stage || MFMA interleave; counted vmcnt(4)
// only at phases 3 and 7 (before the closing barrier); XOR-swizzled LDS.
// Even K-tiles -> dbuf0, odd -> dbuf1.
// Stage ledger per iteration (t0=2j, t1=2j+1, t2c/t3c clamped for tail):
//   ph0: A(t1,h0)  ph1: A(t1,h1)  ph2: B(t2,h0)  ph3: B(t2,h1) [vmcnt 4]
//   ph4: A(t2,h0)  ph5: A(t2,h1)  ph6: B(t3,h0)  ph7: B(t3,h1) [vmcnt 4]
// ---------------------------------------------------------------------------
__global__ void __launch_bounds__(512, 2)
lstm_gemm_cell(const unsigned short* __restrict__ A0,
               const unsigned short* __restrict__ A1,
               int Ktot,
               const unsigned short* __restrict__ Bw,
               const float* __restrict__ biasr,
               const float* __restrict__ wi0r,
               const int* __restrict__ xidx,
               int have_x,
               float* __restrict__ Cst,
               unsigned short* __restrict__ Hout) {
  __shared__ unsigned short As[2][256 * 64];
  __shared__ unsigned short Bs[2][256 * 64];

  const int tid  = threadIdx.x;
  const int lane = tid & 63;
  const int wv   = tid >> 6;          // 0..7
  const int wm   = wv >> 2;           // 0..1  (M half)
  const int wn   = wv & 3;            // 0..3  (N quarter)
  const int tile_m = blockIdx.y * 256;
  const int tile_n = blockIdx.x * 256;

  // staging geometry: one gload round = 512 thr x 16B = 64 rows
  const int rowt = tid >> 3;                          // 0..63
  const int cb8  = (tid & 7) * 8;                     // LDS col, linear dest
  const int ce   = (((tid & 7) ^ (rowt & 7)) * 8);    // global col: inv-swizzled src

  const int NK = Ktot >> 6;

  auto stageA = [&](int t, int half) {
    const int d = t & 1;
    const int kb = t << 6;
    const unsigned short* Ap = A0; int kl = kb;
    if (kb >= 1024) { Ap = A1; kl = kb - 1024; }
#pragma unroll
    for (int i = 0; i < 2; ++i) {
      const int row = half * 128 + i * 64 + rowt;
      gload_lds16(Ap + (size_t)(tile_m + row) * H_ + kl + ce, (void*)&As[d][row * 64 + cb8]);
    }
  };
  auto stageB = [&](int t, int half) {
    const int d = t & 1;
    const int kb = t << 6;
#pragma unroll
    for (int i = 0; i < 2; ++i) {
      const int row = half * 128 + i * 64 + rowt;
      gload_lds16(Bw + (size_t)(tile_n + row) * (size_t)Ktot + kb + ce, (void*)&Bs[d][row * 64 + cb8]);
    }
  };

  f32x4 acc[8][4];
#pragma unroll
  for (int m = 0; m < 8; ++m)
#pragma unroll
    for (int n = 0; n < 4; ++n) acc[m][n] = (f32x4)0.f;

  // fragment read geometry (swizzled): row r holds logical byte-col kb at kb^((r&7)<<4)
  const int cl  = lane & 15;
  const int khi = lane >> 4;          // 0..3
  const int Xn  = lane & 7;
  const int ksw0 = ((0 + khi) ^ Xn) * 16;
  const int ksw1 = ((4 + khi) ^ Xn) * 16;

  bf16x8 bfr0[4], bfr1[4];            // B-frags, live across a K-tile's 4 phases

#define DO_PHASE(T_, Q_, LOADB_, STAGE_EXPR_, TAILWAIT_)                          \
  {                                                                               \
    const char* Ab_ = (const char*)&As[(T_) & 1][0] + (wm * 128 + cl) * 128;      \
    bf16x8 a00_ = *(const bf16x8*)(Ab_ + (2 * (Q_) + 0) * 2048 + ksw0);           \
    bf16x8 a01_ = *(const bf16x8*)(Ab_ + (2 * (Q_) + 0) * 2048 + ksw1);           \
    bf16x8 a10_ = *(const bf16x8*)(Ab_ + (2 * (Q_) + 1) * 2048 + ksw0);           \
    bf16x8 a11_ = *(const bf16x8*)(Ab_ + (2 * (Q_) + 1) * 2048 + ksw1);           \
    if (LOADB_) {                                                                 \
      const char* Bb_ = (const char*)&Bs[(T_) & 1][0] + (wn * 64 + cl) * 128;     \
      _Pragma("unroll")                                                           \
      for (int n_ = 0; n_ < 4; ++n_) {                                            \
        bfr0[n_] = *(const bf16x8*)(Bb_ + n_ * 2048 + ksw0);                      \
        bfr1[n_] = *(const bf16x8*)(Bb_ + n_ * 2048 + ksw1);                      \
      }                                                                           \
    }                                                                             \
    STAGE_EXPR_;                                                                  \
    __builtin_amdgcn_s_barrier();                                                 \
    asm volatile("s_waitcnt lgkmcnt(0)" ::: "memory");                            \
    __builtin_amdgcn_sched_barrier(0);                                            \
    __builtin_amdgcn_s_setprio(1);                                                \
    _Pragma("unroll")                                                             \
    for (int n_ = 0; n_ < 4; ++n_) {                                              \
      acc[2*(Q_)+0][n_] = __builtin_amdgcn_mfma_f32_16x16x32_bf16(a00_, bfr0[n_], acc[2*(Q_)+0][n_], 0, 0, 0); \
      acc[2*(Q_)+0][n_] = __builtin_amdgcn_mfma_f32_16x16x32_bf16(a01_, bfr1[n_], acc[2*(Q_)+0][n_], 0, 0, 0); \
      acc[2*(Q_)+1][n_] = __builtin_amdgcn_mfma_f32_16x16x32_bf16(a10_, bfr0[n_], acc[2*(Q_)+1][n_], 0, 0, 0); \
      acc[2*(Q_)+1][n_] = __builtin_amdgcn_mfma_f32_16x16x32_bf16(a11_, bfr1[n_], acc[2*(Q_)+1][n_], 0, 0, 0); \
    }                                                                             \
    __builtin_amdgcn_s_setprio(0);                                                \
    if (TAILWAIT_) {                                                              \
      asm volatile("s_waitcnt vmcnt(4)" ::: "memory");                            \
      __builtin_amdgcn_sched_barrier(0);                                          \
    }                                                                             \
    __builtin_amdgcn_s_barrier();                                                 \
  }

  // ---- prologue: stage t0 fully + t1.B; keep t1.B in flight (vmcnt 4) ----
  stageA(0, 0); stageA(0, 1);
  stageB(0, 0); stageB(0, 1);
  stageB(1, 0); stageB(1, 1);
  asm volatile("s_waitcnt vmcnt(4)" ::: "memory");
  __builtin_amdgcn_sched_barrier(0);
  __builtin_amdgcn_s_barrier();

  const int NIT = NK >> 1;
  for (int j = 0; j < NIT; ++j) {
    const int t0 = 2 * j, t1 = 2 * j + 1;
    const int t2 = (t0 + 2 < NK) ? t0 + 2 : t0;   // clamp: restage self (benign)
    const int t3 = (t1 + 2 < NK) ? t1 + 2 : t1;
    DO_PHASE(t0, 0, 1, stageA(t1, 0), 0);
    DO_PHASE(t0, 1, 0, stageA(t1, 1), 0);
    DO_PHASE(t0, 2, 0, stageB(t2, 0), 0);
    DO_PHASE(t0, 3, 0, stageB(t2, 1), 1);
    DO_PHASE(t1, 0, 1, stageA(t2, 0), 0);
    DO_PHASE(t1, 1, 0, stageA(t2, 1), 0);
    DO_PHASE(t1, 2, 0, stageB(t3, 0), 0);
    DO_PHASE(t1, 3, 0, stageB(t3, 1), 1);
  }
#undef DO_PHASE

  asm volatile("s_waitcnt vmcnt(0)" ::: "memory");   // drain redundant tail stages

  // ---- epilogue: fused LSTM cell (gate = n-frag index) ----
  const int jgrp = (tile_n >> 6) + wn;
  const int j = jgrp * 16 + cl;
  float bias[4], w0v[4] = {0, 0, 0, 0}, w1v[4] = {0, 0, 0, 0};
#pragma unroll
  for (int n = 0; n < 4; ++n) {
    int colr = tile_n + wn * 64 + n * 16 + cl;
    bias[n] = biasr[colr];
    if (have_x) { w0v[n] = wi0r[colr * 2]; w1v[n] = wi0r[colr * 2 + 1]; }
  }
#pragma unroll
  for (int m = 0; m < 8; ++m) {
#pragma unroll
    for (int q = 0; q < 4; ++q) {
      int row = tile_m + wm * 128 + m * 16 + khi * 4 + q;
      float gi = acc[m][0][q] + bias[0];
      float gf = acc[m][1][q] + bias[1];
      float gg = acc[m][2][q] + bias[2];
      float go = acc[m][3][q] + bias[3];
      if (have_x) {
        int x = xidx[row];
        gi += x ? w1v[0] : w0v[0];
        gf += x ? w1v[1] : w0v[1];
        gg += x ? w1v[2] : w0v[2];
        go += x ? w1v[3] : w0v[3];
      }
      size_t off = (size_t)row * H_ + j;
      float cp = Cst[off];
      float cn = sigm(gf) * cp + sigm(gi) * tanh_(gg);
      float hn = sigm(go) * tanh_(cn);
      Cst[off] = cn;
      Hout[off] = f2bf(hn);
    }
  }
}

// ---------------------------------------------------------------------------
// fc head: logits = h1 @ fcW^T + fcb, write out[b,t,:], argmax -> xidx
// ---------------------------------------------------------------------------
__global__ void fc_argmax(const unsigned short* __restrict__ h1,
                          const float* __restrict__ fcW, const float* __restrict__ fcb,
                          float* __restrict__ out, int* __restrict__ xidx,
                          int t, int pred_len) {
  const int lane = threadIdx.x & 63;
  const int wv = threadIdx.x >> 6;
  const int row = blockIdx.x * 4 + wv;
  const unsigned short* hp = h1 + (size_t)row * H_ + lane * 16;
  float d0 = 0.f, d1 = 0.f;
#pragma unroll
  for (int u = 0; u < 2; ++u) {
    ushort4 ha = *(const ushort4*)(hp + u * 8);
    ushort4 hb = *(const ushort4*)(hp + u * 8 + 4);
    float hv[8] = { bf2f(ha.x), bf2f(ha.y), bf2f(ha.z), bf2f(ha.w),
                    bf2f(hb.x), bf2f(hb.y), bf2f(hb.z), bf2f(hb.w) };
#pragma unroll
    for (int e = 0; e < 8; ++e) {
      int k = lane * 16 + u * 8 + e;
      d0 += hv[e] * fcW[k];
      d1 += hv[e] * fcW[H_ + k];
    }
  }
#pragma unroll
  for (int off = 32; off > 0; off >>= 1) {
    d0 += __shfl_xor(d0, off);
    d1 += __shfl_xor(d1, off);
  }
  if (lane == 0) {
    d0 += fcb[0]; d1 += fcb[1];
    size_t o = ((size_t)row * pred_len + t) * 2;
    out[o] = d0; out[o + 1] = d1;
    xidx[row] = (d1 > d0) ? 1 : 0;
  }
}

// ---------------------------------------------------------------------------
extern "C" void kernel_launch(void* const* d_in, const int* in_sizes, int n_in,
                              void* d_out, int out_size, void* d_ws, size_t ws_size,
                              hipStream_t stream) {
  const float* h     = (const float*)d_in[0];
  const float* c     = (const float*)d_in[1];
  const float* Wih0  = (const float*)d_in[2];
  const float* Whh0  = (const float*)d_in[3];
  const float* bih0  = (const float*)d_in[4];
  const float* bhh0  = (const float*)d_in[5];
  const float* Wih1  = (const float*)d_in[6];
  const float* Whh1  = (const float*)d_in[7];
  const float* bih1  = (const float*)d_in[8];
  const float* bhh1  = (const float*)d_in[9];
  const float* fcW   = (const float*)d_in[10];
  const float* fcb   = (const float*)d_in[11];

  const int B = in_sizes[0] / (2 * H_);           // 4096
  const int pred_len = out_size / (B * 2);        // 64
  const int BH = B * H_;                          // 4194304

  size_t off = 0;
  auto carve = [&](size_t bytes) -> void* {
    void* p = (char*)d_ws + off;
    off += (bytes + 255) & ~(size_t)255;
    return p;
  };
  unsigned short* Whh0r = (unsigned short*)carve((size_t)NG_ * 1024 * 2);
  unsigned short* Wcatr = (unsigned short*)carve((size_t)NG_ * 2048 * 2);
  unsigned short* h0b[2], *h1b[2];
  h0b[0] = (unsigned short*)carve((size_t)BH * 2);
  h0b[1] = (unsigned short*)carve((size_t)BH * 2);
  h1b[0] = (unsigned short*)carve((size_t)BH * 2);
  h1b[1] = (unsigned short*)carve((size_t)BH * 2);
  float* c0 = (float*)carve((size_t)BH * 4);
  float* c1 = (float*)carve((size_t)BH * 4);
  float* bias0r = (float*)carve(NG_ * 4);
  float* bias1r = (float*)carve(NG_ * 4);
  float* wi0r   = (float*)carve(NG_ * 2 * 4);
  int*   xidx   = (int*)carve(B * 4);

  hipLaunchKernelGGL(prep_w0,   dim3((NG_ * 1024 / 4) / 256), dim3(256), 0, stream, Whh0, Whh0r);
  hipLaunchKernelGGL(prep_wcat, dim3((NG_ * 2048 / 4) / 256), dim3(256), 0, stream, Wih1, Whh1, Wcatr);
  hipLaunchKernelGGL(prep_small, dim3(NG_ / 256), dim3(256), 0, stream,
                     Wih0, bih0, bhh0, bih1, bhh1, bias0r, bias1r, wi0r);
  hipLaunchKernelGGL(prep_state, dim3((BH / 4) / 256), dim3(256), 0, stream,
                     h, c, h0b[0], h1b[0], c0, c1, BH);

  dim3 ggrid(NG_ / 256, B / 256);                 // 16 x 16 = 256 blocks (1/CU)
  dim3 gblk(512);
  float* out = (float*)d_out;

  for (int t = 0; t < pred_len; ++t) {
    const int cur = t & 1, nxt = cur ^ 1;
    hipLaunchKernelGGL(lstm_gemm_cell, ggrid, gblk, 0, stream,
                       h0b[cur], (const unsigned short*)nullptr, 1024, Whh0r,
                       bias0r, wi0r, xidx, (t > 0) ? 1 : 0, c0, h0b[nxt]);
    hipLaunchKernelGGL(lstm_gemm_cell, ggrid, gblk, 0, stream,
                       h0b[nxt], h1b[cur], 2048, Wcatr,
                       bias1r, (const float*)nullptr, (const int*)nullptr, 0, c1, h1b[nxt]);
    hipLaunchKernelGGL(fc_argmax, dim3(B / 4), dim3(256), 0, stream,
                       h1b[nxt], fcW, fcb, out, xidx, t, pred_len);
  }
}